// Round 1
// baseline (27.356 us; speedup 1.0000x reference)
//
#include <hip/hip_runtime.h>

#define H_STEPS 200
#define DT 0.01f
#define K_SPRING 100.0f

__device__ __forceinline__ void step(float u, float& x1, float& v1,
                                     float& x2, float& v2) {
    float pen     = x1 + 1.0f - x2;
    float contact = fmaxf(pen, 0.0f);
    float Fc      = -K_SPRING * contact;
    float F1      = u + Fc - v1;      // C = 1
    float F2      = -Fc - v2;
    v1 += F1 * DT;
    v2 += F2 * DT;
    x1 += v1 * DT;
    x2 += v2 * DT;
}

__global__ __launch_bounds__(256)
void pushing_env_kernel(const float* __restrict__ u_seq,
                        const float* __restrict__ x1_0,
                        const float* __restrict__ v1_0,
                        const float* __restrict__ x2_0,
                        const float* __restrict__ v2_0,
                        const float* __restrict__ goal,
                        float* __restrict__ out, int B) {
    int b = blockIdx.x * blockDim.x + threadIdx.x;
    if (b >= B) return;

    float x1 = x1_0[b];
    float v1 = v1_0[b];
    float x2 = x2_0[b];
    float v2 = v2_0[b];
    const float g = goal[0];

    // Each thread streams its own contiguous 800B row via float4 loads.
    const float4* u = reinterpret_cast<const float4*>(u_seq + (size_t)b * H_STEPS);

    #pragma unroll 5
    for (int t = 0; t < H_STEPS / 4; ++t) {
        float4 uu = u[t];
        step(uu.x, x1, v1, x2, v2);
        step(uu.y, x1, v1, x2, v2);
        step(uu.z, x1, v1, x2, v2);
        step(uu.w, x1, v1, x2, v2);
    }

    float d = x2 - g;
    out[b]         = d * d;   // loss
    out[B + b]     = x1;
    out[2 * B + b] = x2;
}

extern "C" void kernel_launch(void* const* d_in, const int* in_sizes, int n_in,
                              void* d_out, int out_size, void* d_ws, size_t ws_size,
                              hipStream_t stream) {
    const float* u_seq = (const float*)d_in[0];
    const float* x1_0  = (const float*)d_in[1];
    const float* v1_0  = (const float*)d_in[2];
    const float* x2_0  = (const float*)d_in[3];
    const float* v2_0  = (const float*)d_in[4];
    const float* goal  = (const float*)d_in[5];
    float* out = (float*)d_out;

    const int B = in_sizes[1];  // 131072
    const int block = 256;
    const int grid = (B + block - 1) / block;
    pushing_env_kernel<<<grid, block, 0, stream>>>(u_seq, x1_0, v1_0, x2_0,
                                                   v2_0, goal, out, B);
}